// Round 14
// baseline (106.151 us; speedup 1.0000x reference)
//
#include <hip/hip_runtime.h>
#include <hip/hip_bf16.h>

#define H 8
#define DMODEL 512
#define DK 64
#define BATCH 4
#define SEQ 2048
#define M_TOTAL (BATCH*SEQ)

typedef short bf16x8 __attribute__((ext_vector_type(8)));
typedef float f32x4 __attribute__((ext_vector_type(4)));
typedef float f32x16 __attribute__((ext_vector_type(16)));

__device__ __forceinline__ unsigned short f2bf(float f) {
    unsigned int u = __builtin_bit_cast(unsigned int, f);
    u += 0x7FFFu + ((u >> 16) & 1u);
    return (unsigned short)(u >> 16);
}

// packed f32x2 -> bf16x2 (RTNE), one VALU op
__device__ __forceinline__ unsigned int pack_bf2(float a, float b) {
    unsigned int r;
    asm("v_cvt_pk_bf16_f32 %0, %1, %2" : "=v"(r) : "v"(a), "v"(b));
    return r;
}

// raw v_exp_f32 (exp2), no libm wrapper
__device__ __forceinline__ float exp2_fast(float x) {
    float r;
    asm("v_exp_f32 %0, %1" : "=v"(r) : "v"(x));
    return r;
}

__device__ __forceinline__ float bf2f(short v) {
    return __builtin_bit_cast(float, ((unsigned int)(unsigned short)v) << 16);
}

__device__ __forceinline__ f32x16 zero16() {
    f32x16 z;
    #pragma unroll
    for (int i = 0; i < 16; i++) z[i] = 0.f;
    return z;
}

// ---------------------------------------------------------------------------
// Merged QKV projection GEMM. 128x64 tile, BK=32, reg-prefetch pipeline.
// (R5 version — frozen.)
// z=0: Q -> bf16 (b,h,s,dk) scaled by 0.125*log2(e)
// z=1: K -> bf16 (b,h,s,dk)
// z=2: V -> bf16 (b,h,dk,s)  (pre-transposed)
// ---------------------------------------------------------------------------
__global__ __launch_bounds__(256) void gemm_qkv(
    const float* __restrict__ query, const float* __restrict__ key_,
    const float* __restrict__ value,
    const float* __restrict__ Wq, const float* __restrict__ bq,
    const float* __restrict__ Wk, const float* __restrict__ bk,
    const float* __restrict__ Wv, const float* __restrict__ bv,
    unsigned short* __restrict__ Qh, unsigned short* __restrict__ Kh,
    unsigned short* __restrict__ Vt)
{
    const int z = blockIdx.z;
    const float* A    = (z == 0) ? query : (z == 1) ? key_ : value;
    const float* W    = (z == 0) ? Wq : (z == 1) ? Wk : Wv;
    const float* bias = (z == 0) ? bq : (z == 1) ? bk : bv;
    unsigned short* out = (z == 0) ? Qh : (z == 1) ? Kh : Vt;

    const int m0 = blockIdx.x * 128;
    const int n0 = blockIdx.y * 64;
    const int tid = threadIdx.x;
    const int lane = tid & 63;
    const int w = tid >> 6;
    const int g = lane >> 4, qi = lane & 15;
    const int wm = w >> 1, wn = w & 1;

    __shared__ unsigned short Alds[128 * 40];
    __shared__ unsigned short Blds[64 * 40];

    f32x4 acc[4][2];
    #pragma unroll
    for (int i = 0; i < 4; i++)
        #pragma unroll
        for (int j = 0; j < 2; j++) acc[i][j] = f32x4{0.f, 0.f, 0.f, 0.f};

    float4 aA[4], bA[2], aB[4], bB[2];

    auto ld = [&](float4 (&ar)[4], float4 (&br)[2], int k0) {
        #pragma unroll
        for (int i = 0; i < 4; i++) { int idx = tid + i * 256;
            ar[i] = *(const float4*)(A + (size_t)(m0 + (idx >> 3)) * 512 + k0 + (idx & 7) * 4); }
        #pragma unroll
        for (int i = 0; i < 2; i++) { int idx = tid + i * 256;
            br[i] = *(const float4*)(W + (size_t)(n0 + (idx >> 3)) * 512 + k0 + (idx & 7) * 4); }
    };
    auto st = [&](float4 (&ar)[4], float4 (&br)[2]) {
        #pragma unroll
        for (int i = 0; i < 4; i++) { int idx = tid + i * 256;
            uint2 p; p.x = pack_bf2(ar[i].x, ar[i].y); p.y = pack_bf2(ar[i].z, ar[i].w);
            *(uint2*)(Alds + (idx >> 3) * 40 + (idx & 7) * 4) = p; }
        #pragma unroll
        for (int i = 0; i < 2; i++) { int idx = tid + i * 256;
            uint2 p; p.x = pack_bf2(br[i].x, br[i].y); p.y = pack_bf2(br[i].z, br[i].w);
            *(uint2*)(Blds + (idx >> 3) * 40 + (idx & 7) * 4) = p; }
    };
    auto tile = [&]() {
        bf16x8 af[4], bf[2];
        #pragma unroll
        for (int mt = 0; mt < 4; mt++)
            af[mt] = *(const bf16x8*)(Alds + (wm * 64 + mt * 16 + qi) * 40 + g * 8);
        #pragma unroll
        for (int nt = 0; nt < 2; nt++)
            bf[nt] = *(const bf16x8*)(Blds + (wn * 32 + nt * 16 + qi) * 40 + g * 8);
        #pragma unroll
        for (int mt = 0; mt < 4; mt++)
            #pragma unroll
            for (int nt = 0; nt < 2; nt++)
                acc[mt][nt] = __builtin_amdgcn_mfma_f32_16x16x32_bf16(af[mt], bf[nt], acc[mt][nt], 0, 0, 0);
    };

    ld(aA, bA, 0);
    for (int k0 = 0; k0 < 512; k0 += 64) {
        __syncthreads();
        st(aA, bA);
        ld(aB, bB, k0 + 32);
        __syncthreads();
        tile();
        __syncthreads();
        st(aB, bB);
        if (k0 + 64 < 512) ld(aA, bA, k0 + 64);
        __syncthreads();
        tile();
    }

    #pragma unroll
    for (int mt = 0; mt < 4; mt++) {
        int mbase = m0 + wm * 64 + mt * 16 + g * 4;
        #pragma unroll
        for (int nt = 0; nt < 2; nt++) {
            int n = n0 + wn * 32 + nt * 16 + qi;
            float bv = bias[n];
            int h = n >> 6, dk = n & 63;
            if (z == 2) {
                int b = mbase >> 11, s = mbase & 2047;
                uint2 pk;
                pk.x = pack_bf2(acc[mt][nt][0] + bv, acc[mt][nt][1] + bv);
                pk.y = pack_bf2(acc[mt][nt][2] + bv, acc[mt][nt][3] + bv);
                *(uint2*)(out + ((size_t)(b * H + h) * 64 + dk) * SEQ + s) = pk;
            } else {
                float sc = (z == 0) ? 0.18033688011112042f : 1.0f;  // (1/8)*log2(e)
                #pragma unroll
                for (int r = 0; r < 4; r++) {
                    int m = mbase + r;
                    int b = m >> 11, s = m & 2047;
                    out[((size_t)(b * H + h) * SEQ + s) * 64 + dk] = f2bf((acc[mt][nt][r] + bv) * sc);
                }
            }
        }
    }
}

// ---------------------------------------------------------------------------
// O projection with fused split-KV merge: A-row = (U0 + U1) * 1/(l0 + l1),
// computed during staging (per 32-K chunk the h-block is fixed: h = k0>>6,
// and l is per (b,h,s)). out = fp32 d_out. Structure = R5 gemm_o.
// ---------------------------------------------------------------------------
__global__ __launch_bounds__(256) void gemm_o(
    const unsigned short* __restrict__ U0, const unsigned short* __restrict__ U1,
    const float* __restrict__ lsum,          // [2][32*2048]
    const float* __restrict__ W,
    const float* __restrict__ bias, float* __restrict__ out)
{
    const int m0 = blockIdx.x * 128;
    const int n0 = blockIdx.y * 64;
    const int tid = threadIdx.x;
    const int lane = tid & 63;
    const int w = tid >> 6;
    const int g = lane >> 4, qi = lane & 15;
    const int wm = w >> 1, wn = w & 1;

    __shared__ unsigned short Alds[128 * 40];
    __shared__ unsigned short Blds[64 * 40];

    f32x4 acc[4][2];
    #pragma unroll
    for (int i = 0; i < 4; i++)
        #pragma unroll
        for (int j = 0; j < 2; j++) acc[i][j] = f32x4{0.f, 0.f, 0.f, 0.f};

    bf16x8 aA[2], aB[2];
    float4 bA[2], bB[2];

    // merged + normalized A load for one 32-K chunk
    auto ld = [&](bf16x8 (&ar)[2], float4 (&br)[2], int k0) {
        const int h = k0 >> 6;
        #pragma unroll
        for (int i = 0; i < 2; i++) {
            int idx = tid + i * 256;
            int m = m0 + (idx >> 2);
            size_t off = (size_t)m * 512 + k0 + (idx & 3) * 8;
            bf16x8 u0 = *(const bf16x8*)(U0 + off);
            bf16x8 u1 = *(const bf16x8*)(U1 + off);
            int lidx = (((m >> 11) * 8 + h) << 11) + (m & 2047);
            float inv = 1.0f / (lsum[lidx] + lsum[65536 + lidx]);
            uint4 p;
            p.x = pack_bf2((bf2f(u0[0]) + bf2f(u1[0])) * inv,
                           (bf2f(u0[1]) + bf2f(u1[1])) * inv);
            p.y = pack_bf2((bf2f(u0[2]) + bf2f(u1[2])) * inv,
                           (bf2f(u0[3]) + bf2f(u1[3])) * inv);
            p.z = pack_bf2((bf2f(u0[4]) + bf2f(u1[4])) * inv,
                           (bf2f(u0[5]) + bf2f(u1[5])) * inv);
            p.w = pack_bf2((bf2f(u0[6]) + bf2f(u1[6])) * inv,
                           (bf2f(u0[7]) + bf2f(u1[7])) * inv);
            ar[i] = __builtin_bit_cast(bf16x8, p);
        }
        #pragma unroll
        for (int i = 0; i < 2; i++) { int idx = tid + i * 256;
            br[i] = *(const float4*)(W + (size_t)(n0 + (idx >> 3)) * 512 + k0 + (idx & 7) * 4); }
    };
    auto st = [&](bf16x8 (&ar)[2], float4 (&br)[2]) {
        #pragma unroll
        for (int i = 0; i < 2; i++) { int idx = tid + i * 256;
            *(bf16x8*)(Alds + (idx >> 2) * 40 + (idx & 3) * 8) = ar[i]; }
        #pragma unroll
        for (int i = 0; i < 2; i++) { int idx = tid + i * 256;
            uint2 p; p.x = pack_bf2(br[i].x, br[i].y); p.y = pack_bf2(br[i].z, br[i].w);
            *(uint2*)(Blds + (idx >> 3) * 40 + (idx & 7) * 4) = p; }
    };
    auto tile = [&]() {
        bf16x8 af[4], bf[2];
        #pragma unroll
        for (int mt = 0; mt < 4; mt++)
            af[mt] = *(const bf16x8*)(Alds + (wm * 64 + mt * 16 + qi) * 40 + g * 8);
        #pragma unroll
        for (int nt = 0; nt < 2; nt++)
            bf[nt] = *(const bf16x8*)(Blds + (wn * 32 + nt * 16 + qi) * 40 + g * 8);
        #pragma unroll
        for (int mt = 0; mt < 4; mt++)
            #pragma unroll
            for (int nt = 0; nt < 2; nt++)
                acc[mt][nt] = __builtin_amdgcn_mfma_f32_16x16x32_bf16(af[mt], bf[nt], acc[mt][nt], 0, 0, 0);
    };

    ld(aA, bA, 0);
    for (int k0 = 0; k0 < 512; k0 += 64) {
        __syncthreads();
        st(aA, bA);
        ld(aB, bB, k0 + 32);
        __syncthreads();
        tile();
        __syncthreads();
        st(aB, bB);
        if (k0 + 64 < 512) ld(aA, bA, k0 + 64);
        __syncthreads();
        tile();
    }

    #pragma unroll
    for (int mt = 0; mt < 4; mt++) {
        int mbase = m0 + wm * 64 + mt * 16 + g * 4;
        #pragma unroll
        for (int nt = 0; nt < 2; nt++) {
            int n = n0 + wn * 32 + nt * 16 + qi;
            float bv = bias[n];
            #pragma unroll
            for (int r = 0; r < 4; r++)
                out[(size_t)(mbase + r) * 512 + n] = acc[mt][nt][r] + bv;
        }
    }
}

// ---------------------------------------------------------------------------
// Flash attention v13 = v10 compute + SPLIT-KV x2:
// grid 1024 (bh, q0, half): each block processes HALF the KV range ->
// 4 blocks/CU x 4 waves = 16 waves/CU = 4 waves/SIMD (v10 was 2/SIMD,
// stall-bound at 51us vs ~20.5us LDS demand). Staging bytes conserved
// (half KV per block, 2x blocks). Fixed-exponent softmax makes the merge
// trivial: unnormalized U and l just ADD — merge fused into gemm_o staging.
// Epilogue writes U (bf16, unnormalized; bf16 rel-precision is scale-
// invariant) + l per (half, bh, s).
// 2-buffer K/V (32KB -> 4 blocks/CU), stage-early + vmcnt(0)+barrier per
// tile (v5/v7-proven pattern; drains hidden by 4x block diversity).
// 32x32x16 MFMA, in-register P via cvt_pk + permlane32_swap.
// ---------------------------------------------------------------------------
__global__ __launch_bounds__(256, 4) void attn_kernel(
    const unsigned short* __restrict__ Qh,
    const unsigned short* __restrict__ Kh,
    const unsigned short* __restrict__ Vt,
    const int* __restrict__ mask,
    unsigned short* __restrict__ Xa0,
    unsigned short* __restrict__ Xa1,
    float* __restrict__ lsum)
{
    const int tid = threadIdx.x;
    const int lane = tid & 63;
    const int w = tid >> 6;        // 0..3
    const int c = lane & 31;       // q column within wave tile
    const int hi = lane >> 5;
    const int x7 = lane & 7;       // row&7 for both K (kv) and V (d) reads

    // XCD swizzle: 1024 blocks; xcd = bid&7 owns bh in [4*xcd, 4*xcd+4)
    const int bid = blockIdx.x;
    const int xcd = bid & 7;
    const int slot = bid >> 3;               // 0..127
    const int bh = xcd * 4 + (slot >> 5);
    const int rem = slot & 31;               // 16 q-tiles x 2 halves
    const int q0 = (rem >> 1) * 128;
    const int half = rem & 1;
    const int b = bh >> 3;

    __shared__ unsigned short Klds[2][64 * 64];   // 2 x 8KB  [kv][d]
    __shared__ unsigned short Vlds[2][64 * 64];   // 2 x 8KB  [d][kv]
    __shared__ int amflag;

    // Q B-fragments: lane (c,hi) holds Q[q=q0+w*32+c][d = seg*16 + hi*8 + j]
    bf16x8 qfr[4];
    {
        const unsigned short* Qbase =
            Qh + ((size_t)bh * SEQ + q0 + w * 32 + c) * 64 + hi * 8;
        #pragma unroll
        for (int seg = 0; seg < 4; seg++)
            qfr[seg] = *(const bf16x8*)(Qbase + seg * 16);
    }

    f32x16 acc[2];
    acc[0] = zero16();
    acc[1] = zero16();
    float l_lane = 0.f;

    const unsigned char* Kbh = (const unsigned char*)(Kh + (size_t)bh * SEQ * 64);
    const unsigned char* Vbh = (const unsigned char*)(Vt + (size_t)bh * 64 * SEQ);
    const int* maskb = mask + b * SEQ;

    // ---- prologue: block-wide "mask all ones?" flag ----
    if (tid == 0) amflag = 1;
    __syncthreads();
    {
        int v = 1;
        #pragma unroll
        for (int i = 0; i < 8; i++) v &= (maskb[tid + i * 256] != 0) ? 1 : 0;
        if (__ballot(v != 0) != ~0ull && lane == 0) amflag = 0;
    }
    __syncthreads();
    const bool allmask = (amflag != 0);

    // staging per-lane source offsets (bytes); 128B logical rows, 8 rows/chunk
    const int klane = ((lane >> 3) << 7)  + (((lane & 7) ^ (lane >> 3)) << 4);   // K row stride 128B
    const int vlane = ((lane >> 3) << 12) + (((lane & 7) ^ (lane >> 3)) << 4);   // V row stride 4096B

    const int krow = c * 128;   // LDS row base (kv=c+32kt for K, d=c+32dt for V)

    auto stage = [&](const unsigned char* ks, const unsigned char* vs, int buf) {
        unsigned char* kd = (unsigned char*)&Klds[buf][0];
        unsigned char* vd = (unsigned char*)&Vlds[buf][0];
        #pragma unroll
        for (int j = 0; j < 2; j++) {
            const int cc = w + 4 * j;   // 8 chunks of 8 rows across 4 waves
            __builtin_amdgcn_global_load_lds(
                (const __attribute__((address_space(1))) unsigned int*)(ks + cc * 1024),
                (__attribute__((address_space(3))) unsigned int*)(kd + cc * 1024), 16, 0, 0);
            __builtin_amdgcn_global_load_lds(
                (const __attribute__((address_space(1))) unsigned int*)(vs + cc * 32768),
                (__attribute__((address_space(3))) unsigned int*)(vd + cc * 1024), 16, 0, 0);
        }
    };

    auto compute = [&](int t, int buf) {
        const unsigned char* KB = (const unsigned char*)&Klds[buf][0];
        const unsigned char* VB = (const unsigned char*)&Vlds[buf][0];
        const int kv0 = (half << 10) + (t << 6);

        unsigned long long mb = ~0ull;
        if (!allmask) mb = __ballot(maskb[kv0 + lane] != 0);

        #pragma unroll
        for (int kt = 0; kt < 2; kt++) {
            // ---- S^T[kv=c+32kt][q] over 4 d-segments ----
            f32x16 sa = zero16();
            __builtin_amdgcn_s_setprio(1);
            #pragma unroll
            for (int seg = 0; seg < 4; seg++) {
                bf16x8 kf = *(const bf16x8*)(
                    KB + kt * 4096 + krow + ((((seg << 1) | hi) ^ x7) << 4));
                sa = __builtin_amdgcn_mfma_f32_32x32x16_bf16(kf, qfr[seg], sa, 0, 0, 0);
            }
            __builtin_amdgcn_s_setprio(0);

            if (mb != ~0ull) {   // rare path (bench mask is all-ones)
                #pragma unroll
                for (int r = 0; r < 16; r++) {
                    int kvl = (r & 3) + 8 * (r >> 2) + 4 * hi + 32 * kt;
                    if (!((mb >> kvl) & 1ull)) sa[r] = -1e9f;
                }
            }

            // ---- P = exp2(S); l partial; pack + permlane32_swap -> B-frags ----
            float pe[16];
            #pragma unroll
            for (int r = 0; r < 16; r++) pe[r] = exp2_fast(sa[r]);
            l_lane += (((pe[0] + pe[1]) + (pe[2] + pe[3])) +
                       ((pe[4] + pe[5]) + (pe[6] + pe[7]))) +
                      (((pe[8] + pe[9]) + (pe[10] + pe[11])) +
                       ((pe[12] + pe[13]) + (pe[14] + pe[15])));

            unsigned int a0 = pack_bf2(pe[0],  pe[1]),  a1 = pack_bf2(pe[2],  pe[3]);
            unsigned int b0 = pack_bf2(pe[4],  pe[5]),  b1 = pack_bf2(pe[6],  pe[7]);
            unsigned int c0 = pack_bf2(pe[8],  pe[9]),  c1 = pack_bf2(pe[10], pe[11]);
            unsigned int d0 = pack_bf2(pe[12], pe[13]), d1 = pack_bf2(pe[14], pe[15]);
            asm("v_permlane32_swap_b32 %0, %1" : "+v"(a0), "+v"(b0));
            asm("v_permlane32_swap_b32 %0, %1" : "+v"(a1), "+v"(b1));
            asm("v_permlane32_swap_b32 %0, %1" : "+v"(c0), "+v"(d0));
            asm("v_permlane32_swap_b32 %0, %1" : "+v"(c1), "+v"(d1));
            uint4 u0 = {a0, a1, b0, b1};   // P[q=c][kv = 16*0 + hi*8 + 0..7]
            uint4 u1 = {c0, c1, d0, d1};   // P[q=c][kv = 16*1 + hi*8 + 0..7]
            bf16x8 pf0 = __builtin_bit_cast(bf16x8, u0);
            bf16x8 pf1 = __builtin_bit_cast(bf16x8, u1);

            // ---- O^T += V^T P^T ----
            __builtin_amdgcn_s_setprio(1);
            #pragma unroll
            for (int dt = 0; dt < 2; dt++) {
                bf16x8 vf0 = *(const bf16x8*)(
                    VB + dt * 4096 + krow + ((((kt << 2) | 0 | hi) ^ x7) << 4));
                acc[dt] = __builtin_amdgcn_mfma_f32_32x32x16_bf16(vf0, pf0, acc[dt], 0, 0, 0);
                bf16x8 vf1 = *(const bf16x8*)(
                    VB + dt * 4096 + krow + ((((kt << 2) | 2 | hi) ^ x7) << 4));
                acc[dt] = __builtin_amdgcn_mfma_f32_32x32x16_bf16(vf1, pf1, acc[dt], 0, 0, 0);
            }
            __builtin_amdgcn_s_setprio(0);
        }
    };

    // half-specific KV base: K rows are 128B; V^T cols are 2B within 4096B rows
    const unsigned char* ks = Kbh + ((size_t)half << 17) + klane;   // +=8192/tile
    const unsigned char* vs = Vbh + (half << 11) + vlane;           // +=128/tile

    // ---- 2-buffer stage-early pipeline, 16 tiles (half KV range) ----
    stage(ks, vs, 0); ks += 8192; vs += 128;
    #pragma unroll 1
    for (int t = 0; t < 16; ++t) {
        __builtin_amdgcn_s_waitcnt(0xF70);   // vmcnt(0): my tile-t loads done
        __builtin_amdgcn_s_barrier();         // all waves done tile t-1 reads
        if (t + 1 < 16) {
            stage(ks, vs, (t + 1) & 1);       // buf free: read finished at t-1
            ks += 8192; vs += 128;
        }
        compute(t, t & 1);
    }

    // ---- epilogue: write UNNORMALIZED U (bf16) + l ----
    const int h = bh & 7;
    float l = l_lane + __shfl_xor(l_lane, 32);
    const int s = q0 + w * 32 + c;
    unsigned short* Xh = half ? Xa1 : Xa0;
    size_t base = ((size_t)b * SEQ + s) * 512 + h * 64;
    #pragma unroll
    for (int dt = 0; dt < 2; dt++) {
        #pragma unroll
        for (int rg = 0; rg < 4; rg++) {
            const int d0i = rg * 8 + hi * 4 + dt * 32;
            uint2 o;
            o.x = pack_bf2(acc[dt][4 * rg],     acc[dt][4 * rg + 1]);
            o.y = pack_bf2(acc[dt][4 * rg + 2], acc[dt][4 * rg + 3]);
            *(uint2*)(Xh + base + d0i) = o;
        }
    }
    if (hi == 0) lsum[(half << 16) + (bh << 11) + s] = l;
}

extern "C" void kernel_launch(void* const* d_in, const int* in_sizes, int n_in,
                              void* d_out, int out_size, void* d_ws, size_t ws_size,
                              hipStream_t stream)
{
    const float* query = (const float*)d_in[0];
    const float* key_  = (const float*)d_in[1];
    const float* value = (const float*)d_in[2];
    const int*   mask  = (const int*)d_in[3];
    const float* Wq = (const float*)d_in[4];
    const float* bq = (const float*)d_in[5];
    const float* Wk = (const float*)d_in[6];
    const float* bk = (const float*)d_in[7];
    const float* Wv = (const float*)d_in[8];
    const float* bv = (const float*)d_in[9];
    const float* Wo = (const float*)d_in[10];
    const float* bo = (const float*)d_in[11];

    // workspace: Qh,Kh,Vt,Xa0,Xa1 (5 x 8.4MB bf16) + lsum (512KB f32) = 42.5MB
    unsigned short* Qh  = (unsigned short*)d_ws;
    unsigned short* Kh  = Qh  + (size_t)M_TOTAL * DMODEL;
    unsigned short* Vt  = Kh  + (size_t)M_TOTAL * DMODEL;
    unsigned short* Xa0 = Vt  + (size_t)M_TOTAL * DMODEL;
    unsigned short* Xa1 = Xa0 + (size_t)M_TOTAL * DMODEL;
    float* lsum = (float*)(Xa1 + (size_t)M_TOTAL * DMODEL);

    hipLaunchKernelGGL(gemm_qkv, dim3(64, 8, 3), dim3(256), 0, stream,
                       query, key_, value, Wq, bq, Wk, bk, Wv, bv, Qh, Kh, Vt);
    hipLaunchKernelGGL(attn_kernel, dim3(1024), dim3(256), 0, stream,
                       Qh, Kh, Vt, mask, Xa0, Xa1, lsum);
    hipLaunchKernelGGL(gemm_o, dim3(64, 8), dim3(256), 0, stream,
                       Xa0, Xa1, lsum, Wo, bo, (float*)d_out);
}

// Round 15
// 93.003 us; speedup vs baseline: 1.1414x; 1.1414x over previous
//
#include <hip/hip_runtime.h>
#include <hip/hip_bf16.h>

#define H 8
#define DMODEL 512
#define DK 64
#define BATCH 4
#define SEQ 2048
#define M_TOTAL (BATCH*SEQ)

typedef short bf16x8 __attribute__((ext_vector_type(8)));
typedef float f32x4 __attribute__((ext_vector_type(4)));
typedef float f32x16 __attribute__((ext_vector_type(16)));

__device__ __forceinline__ unsigned short f2bf(float f) {
    unsigned int u = __builtin_bit_cast(unsigned int, f);
    u += 0x7FFFu + ((u >> 16) & 1u);
    return (unsigned short)(u >> 16);
}

// packed f32x2 -> bf16x2 (RTNE), one VALU op
__device__ __forceinline__ unsigned int pack_bf2(float a, float b) {
    unsigned int r;
    asm("v_cvt_pk_bf16_f32 %0, %1, %2" : "=v"(r) : "v"(a), "v"(b));
    return r;
}

// raw v_exp_f32 (exp2), no libm wrapper
__device__ __forceinline__ float exp2_fast(float x) {
    float r;
    asm("v_exp_f32 %0, %1" : "=v"(r) : "v"(x));
    return r;
}

__device__ __forceinline__ f32x16 zero16() {
    f32x16 z;
    #pragma unroll
    for (int i = 0; i < 16; i++) z[i] = 0.f;
    return z;
}

// ---------------------------------------------------------------------------
// One-shot weight conversion: Wq|Wk|Wv|Wo fp32 -> bf16 (RTNE, identical to
// the per-tile conversion previously done in staging). 2 MB result stays
// L2-resident for the GEMMs. grid 512 x 256 thr, 8 elems/thread.
// ---------------------------------------------------------------------------
__global__ __launch_bounds__(256) void conv_w(
    const float* __restrict__ Wq, const float* __restrict__ Wk,
    const float* __restrict__ Wv, const float* __restrict__ Wo,
    unsigned short* __restrict__ Wb)
{
    int i = blockIdx.x * 256 + threadIdx.x;     // 0..131071
    int z = i >> 15;                             // 32768 threads per matrix
    int e = (i & 32767) * 8;
    const float* s = (z == 0) ? Wq : (z == 1) ? Wk : (z == 2) ? Wv : Wo;
    float4 v0 = *(const float4*)(s + e);
    float4 v1 = *(const float4*)(s + e + 4);
    uint4 p;
    p.x = pack_bf2(v0.x, v0.y); p.y = pack_bf2(v0.z, v0.w);
    p.z = pack_bf2(v1.x, v1.y); p.w = pack_bf2(v1.z, v1.w);
    *(uint4*)(Wb + ((size_t)z << 18) + e) = p;
}

// ---------------------------------------------------------------------------
// Merged QKV projection GEMM. 128x64 tile, BK=32, reg-prefetch pipeline.
// (R5 structure; B path now loads pre-converted bf16 W — 1 load + 1 store
// per thread instead of 2 loads + 4 cvt + 2 stores.)
// z=0: Q -> bf16 (b,h,s,dk) scaled by 0.125*log2(e)
// z=1: K -> bf16 (b,h,s,dk)
// z=2: V -> bf16 (b,h,dk,s)  (pre-transposed)
// ---------------------------------------------------------------------------
__global__ __launch_bounds__(256) void gemm_qkv(
    const float* __restrict__ query, const float* __restrict__ key_,
    const float* __restrict__ value,
    const unsigned short* __restrict__ Wb,
    const float* __restrict__ bq, const float* __restrict__ bk,
    const float* __restrict__ bv,
    unsigned short* __restrict__ Qh, unsigned short* __restrict__ Kh,
    unsigned short* __restrict__ Vt)
{
    const int z = blockIdx.z;
    const float* A    = (z == 0) ? query : (z == 1) ? key_ : value;
    const unsigned short* W = Wb + ((size_t)z << 18);
    const float* bias = (z == 0) ? bq : (z == 1) ? bk : bv;
    unsigned short* out = (z == 0) ? Qh : (z == 1) ? Kh : Vt;

    const int m0 = blockIdx.x * 128;
    const int n0 = blockIdx.y * 64;
    const int tid = threadIdx.x;
    const int lane = tid & 63;
    const int w = tid >> 6;
    const int g = lane >> 4, qi = lane & 15;
    const int wm = w >> 1, wn = w & 1;

    __shared__ unsigned short Alds[128 * 40];
    __shared__ unsigned short Blds[64 * 40];

    f32x4 acc[4][2];
    #pragma unroll
    for (int i = 0; i < 4; i++)
        #pragma unroll
        for (int j = 0; j < 2; j++) acc[i][j] = f32x4{0.f, 0.f, 0.f, 0.f};

    float4 aA[4], aB[4];
    bf16x8 bA, bB;

    auto ld = [&](float4 (&ar)[4], bf16x8& br, int k0) {
        #pragma unroll
        for (int i = 0; i < 4; i++) { int idx = tid + i * 256;
            ar[i] = *(const float4*)(A + (size_t)(m0 + (idx >> 3)) * 512 + k0 + (idx & 7) * 4); }
        br = *(const bf16x8*)(W + (size_t)(n0 + (tid >> 2)) * 512 + k0 + (tid & 3) * 8);
    };
    auto st = [&](float4 (&ar)[4], bf16x8& br) {
        #pragma unroll
        for (int i = 0; i < 4; i++) { int idx = tid + i * 256;
            uint2 p; p.x = pack_bf2(ar[i].x, ar[i].y); p.y = pack_bf2(ar[i].z, ar[i].w);
            *(uint2*)(Alds + (idx >> 3) * 40 + (idx & 7) * 4) = p; }
        *(bf16x8*)(Blds + (tid >> 2) * 40 + (tid & 3) * 8) = br;
    };
    auto tile = [&]() {
        bf16x8 af[4], bf[2];
        #pragma unroll
        for (int mt = 0; mt < 4; mt++)
            af[mt] = *(const bf16x8*)(Alds + (wm * 64 + mt * 16 + qi) * 40 + g * 8);
        #pragma unroll
        for (int nt = 0; nt < 2; nt++)
            bf[nt] = *(const bf16x8*)(Blds + (wn * 32 + nt * 16 + qi) * 40 + g * 8);
        #pragma unroll
        for (int mt = 0; mt < 4; mt++)
            #pragma unroll
            for (int nt = 0; nt < 2; nt++)
                acc[mt][nt] = __builtin_amdgcn_mfma_f32_16x16x32_bf16(af[mt], bf[nt], acc[mt][nt], 0, 0, 0);
    };

    ld(aA, bA, 0);
    for (int k0 = 0; k0 < 512; k0 += 64) {
        __syncthreads();
        st(aA, bA);
        ld(aB, bB, k0 + 32);
        __syncthreads();
        tile();
        __syncthreads();
        st(aB, bB);
        if (k0 + 64 < 512) ld(aA, bA, k0 + 64);
        __syncthreads();
        tile();
    }

    #pragma unroll
    for (int mt = 0; mt < 4; mt++) {
        int mbase = m0 + wm * 64 + mt * 16 + g * 4;
        #pragma unroll
        for (int nt = 0; nt < 2; nt++) {
            int n = n0 + wn * 32 + nt * 16 + qi;
            float bv = bias[n];
            int h = n >> 6, dk = n & 63;
            if (z == 2) {
                int b = mbase >> 11, s = mbase & 2047;
                uint2 pk;
                pk.x = pack_bf2(acc[mt][nt][0] + bv, acc[mt][nt][1] + bv);
                pk.y = pack_bf2(acc[mt][nt][2] + bv, acc[mt][nt][3] + bv);
                *(uint2*)(out + ((size_t)(b * H + h) * 64 + dk) * SEQ + s) = pk;
            } else {
                float sc = (z == 0) ? 0.18033688011112042f : 1.0f;  // (1/8)*log2(e)
                #pragma unroll
                for (int r = 0; r < 4; r++) {
                    int m = mbase + r;
                    int b = m >> 11, s = m & 2047;
                    out[((size_t)(b * H + h) * SEQ + s) * 64 + dk] = f2bf((acc[mt][nt][r] + bv) * sc);
                }
            }
        }
    }
}

// ---------------------------------------------------------------------------
// O projection: A = Xattn (bf16), out = fp32 d_out. (R5 structure; B path
// uses pre-converted bf16 Wo.)
// ---------------------------------------------------------------------------
__global__ __launch_bounds__(256) void gemm_o(
    const unsigned short* __restrict__ Xa, const unsigned short* __restrict__ Wo,
    const float* __restrict__ bias, float* __restrict__ out)
{
    const int m0 = blockIdx.x * 128;
    const int n0 = blockIdx.y * 64;
    const int tid = threadIdx.x;
    const int lane = tid & 63;
    const int w = tid >> 6;
    const int g = lane >> 4, qi = lane & 15;
    const int wm = w >> 1, wn = w & 1;

    __shared__ unsigned short Alds[128 * 40];
    __shared__ unsigned short Blds[64 * 40];

    f32x4 acc[4][2];
    #pragma unroll
    for (int i = 0; i < 4; i++)
        #pragma unroll
        for (int j = 0; j < 2; j++) acc[i][j] = f32x4{0.f, 0.f, 0.f, 0.f};

    bf16x8 aA[2], aB[2], bA, bB;

    auto ld = [&](bf16x8 (&ar)[2], bf16x8& br, int k0) {
        #pragma unroll
        for (int i = 0; i < 2; i++) { int idx = tid + i * 256;
            ar[i] = *(const bf16x8*)(Xa + (size_t)(m0 + (idx >> 2)) * 512 + k0 + (idx & 3) * 8); }
        br = *(const bf16x8*)(Wo + (size_t)(n0 + (tid >> 2)) * 512 + k0 + (tid & 3) * 8);
    };
    auto st = [&](bf16x8 (&ar)[2], bf16x8& br) {
        #pragma unroll
        for (int i = 0; i < 2; i++) { int idx = tid + i * 256;
            *(bf16x8*)(Alds + (idx >> 2) * 40 + (idx & 3) * 8) = ar[i]; }
        *(bf16x8*)(Blds + (tid >> 2) * 40 + (tid & 3) * 8) = br;
    };
    auto tile = [&]() {
        bf16x8 af[4], bf[2];
        #pragma unroll
        for (int mt = 0; mt < 4; mt++)
            af[mt] = *(const bf16x8*)(Alds + (wm * 64 + mt * 16 + qi) * 40 + g * 8);
        #pragma unroll
        for (int nt = 0; nt < 2; nt++)
            bf[nt] = *(const bf16x8*)(Blds + (wn * 32 + nt * 16 + qi) * 40 + g * 8);
        #pragma unroll
        for (int mt = 0; mt < 4; mt++)
            #pragma unroll
            for (int nt = 0; nt < 2; nt++)
                acc[mt][nt] = __builtin_amdgcn_mfma_f32_16x16x32_bf16(af[mt], bf[nt], acc[mt][nt], 0, 0, 0);
    };

    ld(aA, bA, 0);
    for (int k0 = 0; k0 < 512; k0 += 64) {
        __syncthreads();
        st(aA, bA);
        ld(aB, bB, k0 + 32);
        __syncthreads();
        tile();
        __syncthreads();
        st(aB, bB);
        if (k0 + 64 < 512) ld(aA, bA, k0 + 64);
        __syncthreads();
        tile();
    }

    #pragma unroll
    for (int mt = 0; mt < 4; mt++) {
        int mbase = m0 + wm * 64 + mt * 16 + g * 4;
        #pragma unroll
        for (int nt = 0; nt < 2; nt++) {
            int n = n0 + wn * 32 + nt * 16 + qi;
            float bv = bias[n];
            #pragma unroll
            for (int r = 0; r < 4; r++)
                out[(size_t)(mbase + r) * 512 + n] = acc[mt][nt][r] + bv;
        }
    }
}

// ---------------------------------------------------------------------------
// Flash attention v10 (best-known: 51.2us). 32x32x16 MFMA, in-register P via
// cvt_pk + permlane32_swap, 4 waves x 32 q, grid 512. 3-buffer K/V, counted
// vmcnt(4) + raw s_barrier. global_load_lds w16, pre-swizzled source
// slot^(row&7), XOR on ds_reads. Fixed-exponent softmax, raw v_exp_f32;
// l = own + xor32. LDS: K 3x8KB + V 3x8KB = 48KB.
// ---------------------------------------------------------------------------
__global__ __launch_bounds__(256, 2) void attn_kernel(
    const unsigned short* __restrict__ Qh,
    const unsigned short* __restrict__ Kh,
    const unsigned short* __restrict__ Vt,
    const int* __restrict__ mask,
    unsigned short* __restrict__ Xattn)
{
    const int tid = threadIdx.x;
    const int lane = tid & 63;
    const int w = tid >> 6;        // 0..3
    const int c = lane & 31;       // q column within wave tile
    const int hi = lane >> 5;
    const int x7 = lane & 7;       // row&7 for both K (kv) and V (d) reads

    // XCD swizzle: 512 blocks; xcd = bid&7 owns bh in [4*xcd, 4*xcd+4)
    const int bid = blockIdx.x;
    const int xcd = bid & 7;
    const int slot = bid >> 3;               // 0..63
    const int bh = xcd * 4 + (slot >> 4);
    const int q0 = (slot & 15) * 128;
    const int b = bh >> 3;

    __shared__ unsigned short Klds[3][64 * 64];   // 3 x 8KB  [kv][d]
    __shared__ unsigned short Vlds[3][64 * 64];   // 3 x 8KB  [d][kv]
    __shared__ int amflag;

    // Q B-fragments: lane (c,hi) holds Q[q=q0+w*32+c][d = seg*16 + hi*8 + j]
    bf16x8 qfr[4];
    {
        const unsigned short* Qbase =
            Qh + ((size_t)bh * SEQ + q0 + w * 32 + c) * 64 + hi * 8;
        #pragma unroll
        for (int seg = 0; seg < 4; seg++)
            qfr[seg] = *(const bf16x8*)(Qbase + seg * 16);
    }

    f32x16 acc[2];
    acc[0] = zero16();
    acc[1] = zero16();
    float l_lane = 0.f;

    const unsigned char* Kbh = (const unsigned char*)(Kh + (size_t)bh * SEQ * 64);
    const unsigned char* Vbh = (const unsigned char*)(Vt + (size_t)bh * 64 * SEQ);
    const int* maskb = mask + b * SEQ;

    // ---- prologue: block-wide "mask all ones?" flag ----
    if (tid == 0) amflag = 1;
    __syncthreads();
    {
        int v = 1;
        #pragma unroll
        for (int i = 0; i < 8; i++) v &= (maskb[tid + i * 256] != 0) ? 1 : 0;
        if (__ballot(v != 0) != ~0ull && lane == 0) amflag = 0;
    }
    __syncthreads();
    const bool allmask = (amflag != 0);

    // staging per-lane source offsets (bytes); 128B logical rows, 8 rows/chunk
    const int klane = ((lane >> 3) << 7)  + (((lane & 7) ^ (lane >> 3)) << 4);   // K row stride 128B
    const int vlane = ((lane >> 3) << 12) + (((lane & 7) ^ (lane >> 3)) << 4);   // V row stride 4096B

    const int krow = c * 128;   // LDS row base (kv=c+32kt for K, d=c+32dt for V)

    auto stage = [&](const unsigned char* ks, const unsigned char* vs, int buf) {
        unsigned char* kd = (unsigned char*)&Klds[buf][0];
        unsigned char* vd = (unsigned char*)&Vlds[buf][0];
        #pragma unroll
        for (int j = 0; j < 2; j++) {
            const int cc = w + 4 * j;   // 8 chunks of 8 rows across 4 waves
            __builtin_amdgcn_global_load_lds(
                (const __attribute__((address_space(1))) unsigned int*)(ks + cc * 1024),
                (__attribute__((address_space(3))) unsigned int*)(kd + cc * 1024), 16, 0, 0);
            __builtin_amdgcn_global_load_lds(
                (const __attribute__((address_space(1))) unsigned int*)(vs + cc * 32768),
                (__attribute__((address_space(3))) unsigned int*)(vd + cc * 1024), 16, 0, 0);
        }
    };

    auto compute = [&](int t, int buf) {
        const unsigned char* KB = (const unsigned char*)&Klds[buf][0];
        const unsigned char* VB = (const unsigned char*)&Vlds[buf][0];
        const int kv0 = t << 6;

        unsigned long long mb = ~0ull;
        if (!allmask) mb = __ballot(maskb[kv0 + lane] != 0);

        #pragma unroll
        for (int kt = 0; kt < 2; kt++) {
            // ---- S^T[kv=c+32kt][q] over 4 d-segments ----
            f32x16 sa = zero16();
            __builtin_amdgcn_s_setprio(1);
            #pragma unroll
            for (int seg = 0; seg < 4; seg++) {
                bf16x8 kf = *(const bf16x8*)(
                    KB + kt * 4096 + krow + ((((seg << 1) | hi) ^ x7) << 4));
                sa = __builtin_amdgcn_mfma_f32_32x32x16_bf16(kf, qfr[seg], sa, 0, 0, 0);
            }
            __builtin_amdgcn_s_setprio(0);

            if (mb != ~0ull) {   // rare path (bench mask is all-ones)
                #pragma unroll
                for (int r = 0; r < 16; r++) {
                    int kvl = (r & 3) + 8 * (r >> 2) + 4 * hi + 32 * kt;
                    if (!((mb >> kvl) & 1ull)) sa[r] = -1e9f;
                }
            }

            // ---- P = exp2(S); l partial; pack + permlane32_swap -> B-frags ----
            float pe[16];
            #pragma unroll
            for (int r = 0; r < 16; r++) pe[r] = exp2_fast(sa[r]);
            l_lane += (((pe[0] + pe[1]) + (pe[2] + pe[3])) +
                       ((pe[4] + pe[5]) + (pe[6] + pe[7]))) +
                      (((pe[8] + pe[9]) + (pe[10] + pe[11])) +
                       ((pe[12] + pe[13]) + (pe[14] + pe[15])));

            unsigned int a0 = pack_bf2(pe[0],  pe[1]),  a1 = pack_bf2(pe[2],  pe[3]);
            unsigned int b0 = pack_bf2(pe[4],  pe[5]),  b1 = pack_bf2(pe[6],  pe[7]);
            unsigned int c0 = pack_bf2(pe[8],  pe[9]),  c1 = pack_bf2(pe[10], pe[11]);
            unsigned int d0 = pack_bf2(pe[12], pe[13]), d1 = pack_bf2(pe[14], pe[15]);
            asm("v_permlane32_swap_b32 %0, %1" : "+v"(a0), "+v"(b0));
            asm("v_permlane32_swap_b32 %0, %1" : "+v"(a1), "+v"(b1));
            asm("v_permlane32_swap_b32 %0, %1" : "+v"(c0), "+v"(d0));
            asm("v_permlane32_swap_b32 %0, %1" : "+v"(c1), "+v"(d1));
            uint4 u0 = {a0, a1, b0, b1};   // P[q=c][kv = 16*0 + hi*8 + 0..7]
            uint4 u1 = {c0, c1, d0, d1};   // P[q=c][kv = 16*1 + hi*8 + 0..7]
            bf16x8 pf0 = __builtin_bit_cast(bf16x8, u0);
            bf16x8 pf1 = __builtin_bit_cast(bf16x8, u1);

            // ---- O^T += V^T P^T ----
            __builtin_amdgcn_s_setprio(1);
            #pragma unroll
            for (int dt = 0; dt < 2; dt++) {
                bf16x8 vf0 = *(const bf16x8*)(
                    VB + dt * 4096 + krow + ((((kt << 2) | 0 | hi) ^ x7) << 4));
                acc[dt] = __builtin_amdgcn_mfma_f32_32x32x16_bf16(vf0, pf0, acc[dt], 0, 0, 0);
                bf16x8 vf1 = *(const bf16x8*)(
                    VB + dt * 4096 + krow + ((((kt << 2) | 2 | hi) ^ x7) << 4));
                acc[dt] = __builtin_amdgcn_mfma_f32_32x32x16_bf16(vf1, pf1, acc[dt], 0, 0, 0);
            }
            __builtin_amdgcn_s_setprio(0);
        }
    };

    const unsigned char* ks = Kbh + klane;   // advances 8192 B / tile
    const unsigned char* vs = Vbh + vlane;   // advances 128 B / tile

    // ---- 3-buffer counted-vmcnt pipeline (4 loads/wave/tile) ----
    stage(ks, vs, 0); ks += 8192; vs += 128;      // tile 0 -> buf 0
    stage(ks, vs, 1); ks += 8192; vs += 128;      // tile 1 -> buf 1
    int bc = 0, bs = 2;                            // compute buf, stage buf
    #pragma unroll 1
    for (int t = 0; t < 32; ++t) {
        // vmcnt(4): my 4 loads for tile t done; tile t+1's 4 stay in flight.
        // imm = lgkmcnt(15)<<8 | expcnt(7)<<4 | vmcnt_lo
        if (t < 31) __builtin_amdgcn_s_waitcnt(0xF74);   // vmcnt(4)
        else        __builtin_amdgcn_s_waitcnt(0xF70);   // vmcnt(0), tail
        __builtin_amdgcn_s_barrier();
        compute(t, bc);
        if (t + 2 < 32) {
            stage(ks, vs, bs);                     // overwrites buf read at t-1
            ks += 8192; vs += 128;
        }
        bc = (bc == 2) ? 0 : bc + 1;
        bs = (bs == 2) ? 0 : bs + 1;
    }

    // ---- epilogue: l = own + partner(lane^32); normalize; write ----
    const int h = bh & 7;
    float l = l_lane + __shfl_xor(l_lane, 32);
    const float inv = 1.0f / l;
    const int s = q0 + w * 32 + c;
    size_t base = ((size_t)b * SEQ + s) * 512 + h * 64;
    #pragma unroll
    for (int dt = 0; dt < 2; dt++) {
        #pragma unroll
        for (int rg = 0; rg < 4; rg++) {
            const int d0i = rg * 8 + hi * 4 + dt * 32;
            uint2 o;
            o.x = pack_bf2(acc[dt][4 * rg]     * inv, acc[dt][4 * rg + 1] * inv);
            o.y = pack_bf2(acc[dt][4 * rg + 2] * inv, acc[dt][4 * rg + 3] * inv);
            *(uint2*)(Xattn + base + d0i) = o;
        }
    }
}

extern "C" void kernel_launch(void* const* d_in, const int* in_sizes, int n_in,
                              void* d_out, int out_size, void* d_ws, size_t ws_size,
                              hipStream_t stream)
{
    const float* query = (const float*)d_in[0];
    const float* key_  = (const float*)d_in[1];
    const float* value = (const float*)d_in[2];
    const int*   mask  = (const int*)d_in[3];
    const float* Wq = (const float*)d_in[4];
    const float* bq = (const float*)d_in[5];
    const float* Wk = (const float*)d_in[6];
    const float* bk = (const float*)d_in[7];
    const float* Wv = (const float*)d_in[8];
    const float* bv = (const float*)d_in[9];
    const float* Wo = (const float*)d_in[10];
    const float* bo = (const float*)d_in[11];

    // workspace: Qh,Kh,Vt,Xa (4 x 8.4MB bf16) + Wb (2MB bf16) = ~35.5MB
    unsigned short* Qh = (unsigned short*)d_ws;
    unsigned short* Kh = Qh + (size_t)M_TOTAL * DMODEL;
    unsigned short* Vt = Kh + (size_t)M_TOTAL * DMODEL;
    unsigned short* Xa = Vt + (size_t)M_TOTAL * DMODEL;
    unsigned short* Wb = Xa + (size_t)M_TOTAL * DMODEL;

    hipLaunchKernelGGL(conv_w, dim3(512), dim3(256), 0, stream, Wq, Wk, Wv, Wo, Wb);
    hipLaunchKernelGGL(gemm_qkv, dim3(64, 8, 3), dim3(256), 0, stream,
                       query, key_, value, Wb, bq, bk, bv, Qh, Kh, Vt);
    hipLaunchKernelGGL(attn_kernel, dim3(512), dim3(256), 0, stream, Qh, Kh, Vt, mask, Xa);
    hipLaunchKernelGGL(gemm_o, dim3(64, 8), dim3(256), 0, stream,
                       Xa, Wb + ((size_t)3 << 18), bo, (float*)d_out);
}

// Round 16
// 88.763 us; speedup vs baseline: 1.1959x; 1.0478x over previous
//
#include <hip/hip_runtime.h>
#include <hip/hip_bf16.h>

#define H 8
#define DMODEL 512
#define DK 64
#define BATCH 4
#define SEQ 2048
#define M_TOTAL (BATCH*SEQ)

typedef short bf16x8 __attribute__((ext_vector_type(8)));
typedef float f32x4 __attribute__((ext_vector_type(4)));
typedef float f32x16 __attribute__((ext_vector_type(16)));

__device__ __forceinline__ unsigned short f2bf(float f) {
    unsigned int u = __builtin_bit_cast(unsigned int, f);
    u += 0x7FFFu + ((u >> 16) & 1u);
    return (unsigned short)(u >> 16);
}

// packed f32x2 -> bf16x2 (RTNE), one VALU op
__device__ __forceinline__ unsigned int pack_bf2(float a, float b) {
    unsigned int r;
    asm("v_cvt_pk_bf16_f32 %0, %1, %2" : "=v"(r) : "v"(a), "v"(b));
    return r;
}

// raw v_exp_f32 (exp2), no libm wrapper
__device__ __forceinline__ float exp2_fast(float x) {
    float r;
    asm("v_exp_f32 %0, %1" : "=v"(r) : "v"(x));
    return r;
}

__device__ __forceinline__ f32x16 zero16() {
    f32x16 z;
    #pragma unroll
    for (int i = 0; i < 16; i++) z[i] = 0.f;
    return z;
}

// ---------------------------------------------------------------------------
// Merged QKV projection GEMM. 128x64 tile, BK=32, reg-prefetch pipeline.
// (R5 version — frozen best-known.)
// z=0: Q -> bf16 (b,h,s,dk) scaled by 0.125*log2(e)
// z=1: K -> bf16 (b,h,s,dk)
// z=2: V -> bf16 (b,h,dk,s)  (pre-transposed)
// ---------------------------------------------------------------------------
__global__ __launch_bounds__(256) void gemm_qkv(
    const float* __restrict__ query, const float* __restrict__ key_,
    const float* __restrict__ value,
    const float* __restrict__ Wq, const float* __restrict__ bq,
    const float* __restrict__ Wk, const float* __restrict__ bk,
    const float* __restrict__ Wv, const float* __restrict__ bv,
    unsigned short* __restrict__ Qh, unsigned short* __restrict__ Kh,
    unsigned short* __restrict__ Vt)
{
    const int z = blockIdx.z;
    const float* A    = (z == 0) ? query : (z == 1) ? key_ : value;
    const float* W    = (z == 0) ? Wq : (z == 1) ? Wk : Wv;
    const float* bias = (z == 0) ? bq : (z == 1) ? bk : bv;
    unsigned short* out = (z == 0) ? Qh : (z == 1) ? Kh : Vt;

    const int m0 = blockIdx.x * 128;
    const int n0 = blockIdx.y * 64;
    const int tid = threadIdx.x;
    const int lane = tid & 63;
    const int w = tid >> 6;
    const int g = lane >> 4, qi = lane & 15;
    const int wm = w >> 1, wn = w & 1;

    __shared__ unsigned short Alds[128 * 40];
    __shared__ unsigned short Blds[64 * 40];

    f32x4 acc[4][2];
    #pragma unroll
    for (int i = 0; i < 4; i++)
        #pragma unroll
        for (int j = 0; j < 2; j++) acc[i][j] = f32x4{0.f, 0.f, 0.f, 0.f};

    float4 aA[4], bA[2], aB[4], bB[2];

    auto ld = [&](float4 (&ar)[4], float4 (&br)[2], int k0) {
        #pragma unroll
        for (int i = 0; i < 4; i++) { int idx = tid + i * 256;
            ar[i] = *(const float4*)(A + (size_t)(m0 + (idx >> 3)) * 512 + k0 + (idx & 7) * 4); }
        #pragma unroll
        for (int i = 0; i < 2; i++) { int idx = tid + i * 256;
            br[i] = *(const float4*)(W + (size_t)(n0 + (idx >> 3)) * 512 + k0 + (idx & 7) * 4); }
    };
    auto st = [&](float4 (&ar)[4], float4 (&br)[2]) {
        #pragma unroll
        for (int i = 0; i < 4; i++) { int idx = tid + i * 256;
            uint2 p; p.x = pack_bf2(ar[i].x, ar[i].y); p.y = pack_bf2(ar[i].z, ar[i].w);
            *(uint2*)(Alds + (idx >> 3) * 40 + (idx & 7) * 4) = p; }
        #pragma unroll
        for (int i = 0; i < 2; i++) { int idx = tid + i * 256;
            uint2 p; p.x = pack_bf2(br[i].x, br[i].y); p.y = pack_bf2(br[i].z, br[i].w);
            *(uint2*)(Blds + (idx >> 3) * 40 + (idx & 7) * 4) = p; }
    };
    auto tile = [&]() {
        bf16x8 af[4], bf[2];
        #pragma unroll
        for (int mt = 0; mt < 4; mt++)
            af[mt] = *(const bf16x8*)(Alds + (wm * 64 + mt * 16 + qi) * 40 + g * 8);
        #pragma unroll
        for (int nt = 0; nt < 2; nt++)
            bf[nt] = *(const bf16x8*)(Blds + (wn * 32 + nt * 16 + qi) * 40 + g * 8);
        #pragma unroll
        for (int mt = 0; mt < 4; mt++)
            #pragma unroll
            for (int nt = 0; nt < 2; nt++)
                acc[mt][nt] = __builtin_amdgcn_mfma_f32_16x16x32_bf16(af[mt], bf[nt], acc[mt][nt], 0, 0, 0);
    };

    ld(aA, bA, 0);
    for (int k0 = 0; k0 < 512; k0 += 64) {
        __syncthreads();
        st(aA, bA);
        ld(aB, bB, k0 + 32);
        __syncthreads();
        tile();
        __syncthreads();
        st(aB, bB);
        if (k0 + 64 < 512) ld(aA, bA, k0 + 64);
        __syncthreads();
        tile();
    }

    #pragma unroll
    for (int mt = 0; mt < 4; mt++) {
        int mbase = m0 + wm * 64 + mt * 16 + g * 4;
        #pragma unroll
        for (int nt = 0; nt < 2; nt++) {
            int n = n0 + wn * 32 + nt * 16 + qi;
            float bv = bias[n];
            int h = n >> 6, dk = n & 63;
            if (z == 2) {
                int b = mbase >> 11, s = mbase & 2047;
                uint2 pk;
                pk.x = pack_bf2(acc[mt][nt][0] + bv, acc[mt][nt][1] + bv);
                pk.y = pack_bf2(acc[mt][nt][2] + bv, acc[mt][nt][3] + bv);
                *(uint2*)(out + ((size_t)(b * H + h) * 64 + dk) * SEQ + s) = pk;
            } else {
                float sc = (z == 0) ? 0.18033688011112042f : 1.0f;  // (1/8)*log2(e)
                #pragma unroll
                for (int r = 0; r < 4; r++) {
                    int m = mbase + r;
                    int b = m >> 11, s = m & 2047;
                    out[((size_t)(b * H + h) * SEQ + s) * 64 + dk] = f2bf((acc[mt][nt][r] + bv) * sc);
                }
            }
        }
    }
}

// ---------------------------------------------------------------------------
// O projection: A = Xattn (bf16), out = fp32 d_out. (R5 version — frozen.)
// ---------------------------------------------------------------------------
__global__ __launch_bounds__(256) void gemm_o(
    const unsigned short* __restrict__ Xa, const float* __restrict__ W,
    const float* __restrict__ bias, float* __restrict__ out)
{
    const int m0 = blockIdx.x * 128;
    const int n0 = blockIdx.y * 64;
    const int tid = threadIdx.x;
    const int lane = tid & 63;
    const int w = tid >> 6;
    const int g = lane >> 4, qi = lane & 15;
    const int wm = w >> 1, wn = w & 1;

    __shared__ unsigned short Alds[128 * 40];
    __shared__ unsigned short Blds[64 * 40];

    f32x4 acc[4][2];
    #pragma unroll
    for (int i = 0; i < 4; i++)
        #pragma unroll
        for (int j = 0; j < 2; j++) acc[i][j] = f32x4{0.f, 0.f, 0.f, 0.f};

    bf16x8 aA[2], aB[2];
    float4 bA[2], bB[2];

    auto ld = [&](bf16x8 (&ar)[2], float4 (&br)[2], int k0) {
        #pragma unroll
        for (int i = 0; i < 2; i++) { int idx = tid + i * 256;
            ar[i] = *(const bf16x8*)(Xa + (size_t)(m0 + (idx >> 2)) * 512 + k0 + (idx & 3) * 8); }
        #pragma unroll
        for (int i = 0; i < 2; i++) { int idx = tid + i * 256;
            br[i] = *(const float4*)(W + (size_t)(n0 + (idx >> 3)) * 512 + k0 + (idx & 7) * 4); }
    };
    auto st = [&](bf16x8 (&ar)[2], float4 (&br)[2]) {
        #pragma unroll
        for (int i = 0; i < 2; i++) { int idx = tid + i * 256;
            *(bf16x8*)(Alds + (idx >> 2) * 40 + (idx & 3) * 8) = ar[i]; }
        #pragma unroll
        for (int i = 0; i < 2; i++) { int idx = tid + i * 256;
            uint2 p; p.x = pack_bf2(br[i].x, br[i].y); p.y = pack_bf2(br[i].z, br[i].w);
            *(uint2*)(Blds + (idx >> 3) * 40 + (idx & 7) * 4) = p; }
    };
    auto tile = [&]() {
        bf16x8 af[4], bf[2];
        #pragma unroll
        for (int mt = 0; mt < 4; mt++)
            af[mt] = *(const bf16x8*)(Alds + (wm * 64 + mt * 16 + qi) * 40 + g * 8);
        #pragma unroll
        for (int nt = 0; nt < 2; nt++)
            bf[nt] = *(const bf16x8*)(Blds + (wn * 32 + nt * 16 + qi) * 40 + g * 8);
        #pragma unroll
        for (int mt = 0; mt < 4; mt++)
            #pragma unroll
            for (int nt = 0; nt < 2; nt++)
                acc[mt][nt] = __builtin_amdgcn_mfma_f32_16x16x32_bf16(af[mt], bf[nt], acc[mt][nt], 0, 0, 0);
    };

    ld(aA, bA, 0);
    for (int k0 = 0; k0 < 512; k0 += 64) {
        __syncthreads();
        st(aA, bA);
        ld(aB, bB, k0 + 32);
        __syncthreads();
        tile();
        __syncthreads();
        st(aB, bB);
        if (k0 + 64 < 512) ld(aA, bA, k0 + 64);
        __syncthreads();
        tile();
    }

    #pragma unroll
    for (int mt = 0; mt < 4; mt++) {
        int mbase = m0 + wm * 64 + mt * 16 + g * 4;
        #pragma unroll
        for (int nt = 0; nt < 2; nt++) {
            int n = n0 + wn * 32 + nt * 16 + qi;
            float bv = bias[n];
            #pragma unroll
            for (int r = 0; r < 4; r++)
                out[(size_t)(mbase + r) * 512 + n] = acc[mt][nt][r] + bv;
        }
    }
}

// ---------------------------------------------------------------------------
// Flash attention v14 = v10 with waves split by (kt, q-half) instead of q:
// wave (ktw = w&1, qh = w>>1) handles kv-subtile ktw (32 rows) x 64 q
// (2 Q-fragments). K/V fragment reads drop to 4 kf + 4 vf b128 per wave
// per tile (HALF of v10's 16 — v10's 4 waves all read identical K/V frags),
// each read feeding 2 MFMAs. MFMA/exp2/staging totals conserved.
// One-time epilogue: cross-kt partial-O sum through LDS (reuses K/V bufs).
// 32x32x16 MFMA, in-register P via cvt_pk + permlane32_swap, grid 512.
// 3-buffer K/V, counted vmcnt(4) + raw s_barrier. global_load_lds w16,
// pre-swizzled source slot^(row&7), XOR on ds_reads. Fixed-exponent softmax.
// LDS: K 3x8KB + V 3x8KB = 48KB.
// ---------------------------------------------------------------------------
__global__ __launch_bounds__(256, 2) void attn_kernel(
    const unsigned short* __restrict__ Qh,
    const unsigned short* __restrict__ Kh,
    const unsigned short* __restrict__ Vt,
    const int* __restrict__ mask,
    unsigned short* __restrict__ Xattn)
{
    const int tid = threadIdx.x;
    const int lane = tid & 63;
    const int w = tid >> 6;        // 0..3
    const int ktw = w & 1;         // kv-subtile owned by this wave
    const int qh = w >> 1;         // q-half owned by this wave
    const int c = lane & 31;
    const int hi = lane >> 5;
    const int x7 = lane & 7;

    // XCD swizzle: 512 blocks; xcd = bid&7 owns bh in [4*xcd, 4*xcd+4)
    const int bid = blockIdx.x;
    const int xcd = bid & 7;
    const int slot = bid >> 3;               // 0..63
    const int bh = xcd * 4 + (slot >> 4);
    const int q0 = (slot & 15) * 128;
    const int b = bh >> 3;

    __shared__ unsigned short Klds[3][64 * 64];   // 3 x 8KB  [kv][d]
    __shared__ unsigned short Vlds[3][64 * 64];   // 3 x 8KB  [d][kv]
    __shared__ int amflag;

    // Q B-fragments: frag f covers q = q0 + qh*64 + f*32 + c
    bf16x8 qfr[2][4];
    #pragma unroll
    for (int f = 0; f < 2; f++) {
        const unsigned short* Qbase =
            Qh + ((size_t)bh * SEQ + q0 + qh * 64 + f * 32 + c) * 64 + hi * 8;
        #pragma unroll
        for (int seg = 0; seg < 4; seg++)
            qfr[f][seg] = *(const bf16x8*)(Qbase + seg * 16);
    }

    f32x16 acc[2][2];   // [qfrag][dt], partial over this wave's kv-subtile
    acc[0][0] = zero16(); acc[0][1] = zero16();
    acc[1][0] = zero16(); acc[1][1] = zero16();
    float l_lane[2] = {0.f, 0.f};

    const unsigned char* Kbh = (const unsigned char*)(Kh + (size_t)bh * SEQ * 64);
    const unsigned char* Vbh = (const unsigned char*)(Vt + (size_t)bh * 64 * SEQ);
    const int* maskb = mask + b * SEQ;

    // ---- prologue: block-wide "mask all ones?" flag ----
    if (tid == 0) amflag = 1;
    __syncthreads();
    {
        int v = 1;
        #pragma unroll
        for (int i = 0; i < 8; i++) v &= (maskb[tid + i * 256] != 0) ? 1 : 0;
        if (__ballot(v != 0) != ~0ull && lane == 0) amflag = 0;
    }
    __syncthreads();
    const bool allmask = (amflag != 0);

    // staging per-lane source offsets (bytes); 128B logical rows, 8 rows/chunk
    const int klane = ((lane >> 3) << 7)  + (((lane & 7) ^ (lane >> 3)) << 4);
    const int vlane = ((lane >> 3) << 12) + (((lane & 7) ^ (lane >> 3)) << 4);

    const int krow = c * 128;   // LDS row base within a 32-row subtile

    auto stage = [&](const unsigned char* ks, const unsigned char* vs, int buf) {
        unsigned char* kd = (unsigned char*)&Klds[buf][0];
        unsigned char* vd = (unsigned char*)&Vlds[buf][0];
        #pragma unroll
        for (int j = 0; j < 2; j++) {
            const int cc = w + 4 * j;
            __builtin_amdgcn_global_load_lds(
                (const __attribute__((address_space(1))) unsigned int*)(ks + cc * 1024),
                (__attribute__((address_space(3))) unsigned int*)(kd + cc * 1024), 16, 0, 0);
            __builtin_amdgcn_global_load_lds(
                (const __attribute__((address_space(1))) unsigned int*)(vs + cc * 32768),
                (__attribute__((address_space(3))) unsigned int*)(vd + cc * 1024), 16, 0, 0);
        }
    };

    auto compute = [&](int t, int buf) {
        const unsigned char* KB = (const unsigned char*)&Klds[buf][0];
        const unsigned char* VB = (const unsigned char*)&Vlds[buf][0];
        const int kv0 = t << 6;

        unsigned long long mb = ~0ull;
        if (!allmask) mb = __ballot(maskb[kv0 + lane] != 0);

        // ---- QK^T: S^T[kv = ktw*32 + crow][q] for both q-fragments ----
        f32x16 sa0 = zero16(), sa1 = zero16();
        __builtin_amdgcn_s_setprio(1);
        #pragma unroll
        for (int seg = 0; seg < 4; seg++) {
            bf16x8 kf = *(const bf16x8*)(
                KB + ktw * 4096 + krow + ((((seg << 1) | hi) ^ x7) << 4));
            sa0 = __builtin_amdgcn_mfma_f32_32x32x16_bf16(kf, qfr[0][seg], sa0, 0, 0, 0);
            sa1 = __builtin_amdgcn_mfma_f32_32x32x16_bf16(kf, qfr[1][seg], sa1, 0, 0, 0);
        }
        __builtin_amdgcn_s_setprio(0);

        if (mb != ~0ull) {   // rare path (bench mask is all-ones)
            #pragma unroll
            for (int r = 0; r < 16; r++) {
                int kvl = (r & 3) + 8 * (r >> 2) + 4 * hi + 32 * ktw;
                if (!((mb >> kvl) & 1ull)) { sa0[r] = -1e9f; sa1[r] = -1e9f; }
            }
        }

        // ---- P = exp2(S); l partials; pack + permlane -> B-frags per f ----
        bf16x8 pf[2][2];
        #pragma unroll
        for (int f = 0; f < 2; f++) {
            const f32x16& sa = f ? sa1 : sa0;
            float pe[16];
            #pragma unroll
            for (int r = 0; r < 16; r++) pe[r] = exp2_fast(sa[r]);
            l_lane[f] += (((pe[0] + pe[1]) + (pe[2] + pe[3])) +
                          ((pe[4] + pe[5]) + (pe[6] + pe[7]))) +
                         (((pe[8] + pe[9]) + (pe[10] + pe[11])) +
                          ((pe[12] + pe[13]) + (pe[14] + pe[15])));
            unsigned int a0 = pack_bf2(pe[0],  pe[1]),  a1 = pack_bf2(pe[2],  pe[3]);
            unsigned int b0 = pack_bf2(pe[4],  pe[5]),  b1 = pack_bf2(pe[6],  pe[7]);
            unsigned int c0 = pack_bf2(pe[8],  pe[9]),  c1 = pack_bf2(pe[10], pe[11]);
            unsigned int d0 = pack_bf2(pe[12], pe[13]), d1 = pack_bf2(pe[14], pe[15]);
            asm("v_permlane32_swap_b32 %0, %1" : "+v"(a0), "+v"(b0));
            asm("v_permlane32_swap_b32 %0, %1" : "+v"(a1), "+v"(b1));
            asm("v_permlane32_swap_b32 %0, %1" : "+v"(c0), "+v"(d0));
            asm("v_permlane32_swap_b32 %0, %1" : "+v"(c1), "+v"(d1));
            uint4 u0 = {a0, a1, b0, b1};   // P[q][kv = ktw*32 + 0  + hi*8 + 0..7]
            uint4 u1 = {c0, c1, d0, d1};   // P[q][kv = ktw*32 + 16 + hi*8 + 0..7]
            pf[f][0] = __builtin_bit_cast(bf16x8, u0);
            pf[f][1] = __builtin_bit_cast(bf16x8, u1);
        }

        // ---- PV: O^T partial over this wave's kv-subtile ----
        __builtin_amdgcn_s_setprio(1);
        #pragma unroll
        for (int dt = 0; dt < 2; dt++) {
            bf16x8 vf0 = *(const bf16x8*)(
                VB + dt * 4096 + krow + ((((ktw << 2) | 0 | hi) ^ x7) << 4));
            acc[0][dt] = __builtin_amdgcn_mfma_f32_32x32x16_bf16(vf0, pf[0][0], acc[0][dt], 0, 0, 0);
            acc[1][dt] = __builtin_amdgcn_mfma_f32_32x32x16_bf16(vf0, pf[1][0], acc[1][dt], 0, 0, 0);
            bf16x8 vf1 = *(const bf16x8*)(
                VB + dt * 4096 + krow + ((((ktw << 2) | 2 | hi) ^ x7) << 4));
            acc[0][dt] = __builtin_amdgcn_mfma_f32_32x32x16_bf16(vf1, pf[0][1], acc[0][dt], 0, 0, 0);
            acc[1][dt] = __builtin_amdgcn_mfma_f32_32x32x16_bf16(vf1, pf[1][1], acc[1][dt], 0, 0, 0);
        }
        __builtin_amdgcn_s_setprio(0);
    };

    const unsigned char* ks = Kbh + klane;   // advances 8192 B / tile
    const unsigned char* vs = Vbh + vlane;   // advances 128 B / tile

    // ---- 3-buffer counted-vmcnt pipeline (4 loads/wave/tile) ----
    stage(ks, vs, 0); ks += 8192; vs += 128;
    stage(ks, vs, 1); ks += 8192; vs += 128;
    int bc = 0, bs = 2;
    #pragma unroll 1
    for (int t = 0; t < 32; ++t) {
        if (t < 31) __builtin_amdgcn_s_waitcnt(0xF74);   // vmcnt(4)
        else        __builtin_amdgcn_s_waitcnt(0xF70);   // vmcnt(0), tail
        __builtin_amdgcn_s_barrier();
        compute(t, bc);
        if (t + 2 < 32) {
            stage(ks, vs, bs);
            ks += 8192; vs += 128;
        }
        bc = (bc == 2) ? 0 : bc + 1;
        bs = (bs == 2) ? 0 : bs + 1;
    }

    // ---- epilogue: cross-kt reduce through LDS, then normalize + write ----
    float l2[2];
    #pragma unroll
    for (int f = 0; f < 2; f++) l2[f] = l_lane[f] + __shfl_xor(l_lane[f], 32);

    __syncthreads();   // all main-loop LDS reads done; safe to repurpose bufs
    // per-qh scratch: qh=0 -> Klds (24KB), qh=1 -> Vlds (24KB). Lane stride
    // 272B (68 floats) breaks the power-of-2 bank alias. l partials at
    // Vlds+20480 (2*2*32 floats).
    float* abuf = (qh == 0) ? (float*)&Klds[0][0] : (float*)&Vlds[0][0];
    float* lb = (float*)((unsigned char*)&Vlds[0][0] + 20480);
    if (ktw == 1) {
        float* dst = abuf + lane * 68;
        #pragma unroll
        for (int f = 0; f < 2; f++)
            #pragma unroll
            for (int dt = 0; dt < 2; dt++)
                #pragma unroll
                for (int rg = 0; rg < 4; rg++) {
                    f32x4 tv = {acc[f][dt][4 * rg],     acc[f][dt][4 * rg + 1],
                                acc[f][dt][4 * rg + 2], acc[f][dt][4 * rg + 3]};
                    *(f32x4*)(dst + (f * 2 + dt) * 16 + rg * 4) = tv;
                }
        if (hi == 0) {
            lb[qh * 64 + c]      = l2[0];
            lb[qh * 64 + 32 + c] = l2[1];
        }
    }
    __syncthreads();
    if (ktw == 0) {
        const float* src = abuf + lane * 68;
        #pragma unroll
        for (int f = 0; f < 2; f++)
            #pragma unroll
            for (int dt = 0; dt < 2; dt++)
                #pragma unroll
                for (int rg = 0; rg < 4; rg++) {
                    f32x4 tv = *(const f32x4*)(src + (f * 2 + dt) * 16 + rg * 4);
                    acc[f][dt][4 * rg]     += tv[0];
                    acc[f][dt][4 * rg + 1] += tv[1];
                    acc[f][dt][4 * rg + 2] += tv[2];
                    acc[f][dt][4 * rg + 3] += tv[3];
                }
        const int h = bh & 7;
        #pragma unroll
        for (int f = 0; f < 2; f++) {
            float inv = 1.0f / (l2[f] + lb[qh * 64 + f * 32 + c]);
            const int s = q0 + qh * 64 + f * 32 + c;
            size_t base = ((size_t)b * SEQ + s) * 512 + h * 64;
            #pragma unroll
            for (int dt = 0; dt < 2; dt++) {
                #pragma unroll
                for (int rg = 0; rg < 4; rg++) {
                    const int d0i = rg * 8 + hi * 4 + dt * 32;
                    uint2 o;
                    o.x = pack_bf2(acc[f][dt][4 * rg]     * inv, acc[f][dt][4 * rg + 1] * inv);
                    o.y = pack_bf2(acc[f][dt][4 * rg + 2] * inv, acc[f][dt][4 * rg + 3] * inv);
                    *(uint2*)(Xattn + base + d0i) = o;
                }
            }
        }
    }
}

extern "C" void kernel_launch(void* const* d_in, const int* in_sizes, int n_in,
                              void* d_out, int out_size, void* d_ws, size_t ws_size,
                              hipStream_t stream)
{
    const float* query = (const float*)d_in[0];
    const float* key_  = (const float*)d_in[1];
    const float* value = (const float*)d_in[2];
    const int*   mask  = (const int*)d_in[3];
    const float* Wq = (const float*)d_in[4];
    const float* bq = (const float*)d_in[5];
    const float* Wk = (const float*)d_in[6];
    const float* bk = (const float*)d_in[7];
    const float* Wv = (const float*)d_in[8];
    const float* bv = (const float*)d_in[9];
    const float* Wo = (const float*)d_in[10];
    const float* bo = (const float*)d_in[11];

    unsigned short* Qh = (unsigned short*)d_ws;
    unsigned short* Kh = Qh + (size_t)M_TOTAL * DMODEL;
    unsigned short* Vt = Kh + (size_t)M_TOTAL * DMODEL;
    unsigned short* Xa = Vt + (size_t)M_TOTAL * DMODEL;

    hipLaunchKernelGGL(gemm_qkv, dim3(64, 8, 3), dim3(256), 0, stream,
                       query, key_, value, Wq, bq, Wk, bk, Wv, bv, Qh, Kh, Vt);
    hipLaunchKernelGGL(attn_kernel, dim3(512), dim3(256), 0, stream, Qh, Kh, Vt, mask, Xa);
    hipLaunchKernelGGL(gemm_o, dim3(64, 8), dim3(256), 0, stream, Xa, Wo, bo, (float*)d_out);
}